// Round 4
// baseline (984.072 us; speedup 1.0000x reference)
//
#include <hip/hip_runtime.h>
#include <hip/hip_bf16.h>
#include <stdint.h>

#define N_NODES 262144
#define N_EDGES 524288
#define EMB 256
#define LN_EPS 1e-5f

typedef unsigned short u16;
typedef unsigned int u32;
typedef __bf16 bf16_t;
typedef __bf16 bf16x8 __attribute__((ext_vector_type(8)));
typedef float f32x4 __attribute__((ext_vector_type(4)));

__device__ __forceinline__ u16 f2bf(float f) {
    u32 u = __float_as_uint(f);
    u32 r = u + 0x7fffu + ((u >> 16) & 1u);
    return (u16)(r >> 16);
}
__device__ __forceinline__ float bf2f(u16 b) { return __uint_as_float(((u32)b) << 16); }
__device__ __forceinline__ float lo16(u32 x) { return __uint_as_float(x << 16); }
__device__ __forceinline__ float hi16(u32 x) { return __uint_as_float(x & 0xffff0000u); }

__device__ __forceinline__ void async_copy16(void* lds, const void* g) {
    __builtin_amdgcn_global_load_lds(
        (const __attribute__((address_space(1))) u32*)g,
        (__attribute__((address_space(3))) u32*)lds, 16, 0, 0);
}

// ---------- convert 4 weight matrices fp32 -> bf16 into ws ----------
__global__ __launch_bounds__(256) void convert_w_kernel(
    const float* __restrict__ a, const float* __restrict__ b,
    const float* __restrict__ c, const float* __restrict__ d,
    u16* __restrict__ out)
{
    int seg = blockIdx.x >> 6;       // 0..3
    int blk = blockIdx.x & 63;       // 0..63
    const float* src = (seg == 0) ? a : (seg == 1) ? b : (seg == 2) ? c : d;
    int off = blk * 1024 + threadIdx.x * 4;
    float4 v = *(const float4*)(src + off);
    uint2 o;
    o.x = (u32)f2bf(v.x) | ((u32)f2bf(v.y) << 16);
    o.y = (u32)f2bf(v.z) | ((u32)f2bf(v.w) << 16);
    *(uint2*)(out + seg * 65536 + off) = o;
}

// ---------- embed + layernorm: one wave per row (fp32 inputs -> bf16 h0) ----------
__global__ __launch_bounds__(256) void embed_ln_kernel(
    const int* __restrict__ node_emb, const int* __restrict__ pos,
    const float* __restrict__ node_tab, const float* __restrict__ pos_tab,
    const float* __restrict__ g_emb, const float* __restrict__ b_emb,
    u16* __restrict__ h0)
{
    const int wid = threadIdx.x >> 6, lane = threadIdx.x & 63;
    const int row = blockIdx.x * 4 + wid;
    const int idx = node_emb[row];
    const int p = pos[row];
    float4 ra = *(const float4*)(node_tab + (size_t)idx * EMB + lane * 4);
    float4 rb = *(const float4*)(pos_tab + (size_t)p * EMB + lane * 4);
    float v0 = ra.x * 16.f + rb.x;
    float v1 = ra.y * 16.f + rb.y;
    float v2 = ra.z * 16.f + rb.z;
    float v3 = ra.w * 16.f + rb.w;
    float s = v0 + v1 + v2 + v3;
    float sq = v0 * v0 + v1 * v1 + v2 * v2 + v3 * v3;
    #pragma unroll
    for (int m = 1; m < 64; m <<= 1) { s += __shfl_xor(s, m); sq += __shfl_xor(sq, m); }
    float mean = s * (1.f / 256.f);
    float var = sq * (1.f / 256.f) - mean * mean;
    float rstd = rsqrtf(var + LN_EPS);
    float4 rg = *(const float4*)(g_emb + lane * 4);
    float4 rbt = *(const float4*)(b_emb + lane * 4);
    float o0 = (v0 - mean) * rstd * rg.x + rbt.x;
    float o1 = (v1 - mean) * rstd * rg.y + rbt.y;
    float o2 = (v2 - mean) * rstd * rg.z + rbt.z;
    float o3 = (v3 - mean) * rstd * rg.w + rbt.w;
    uint2 out;
    out.x = (u32)f2bf(o0) | ((u32)f2bf(o1) << 16);
    out.y = (u32)f2bf(o2) | ((u32)f2bf(o3) << 16);
    *(uint2*)(h0 + (size_t)row * EMB + lane * 4) = out;
}

// ---------- CSR build ----------
__global__ __launch_bounds__(256) void hist_kernel(const int* __restrict__ dst, int* __restrict__ deg) {
    int e = blockIdx.x * 256 + threadIdx.x;
    atomicAdd(&deg[dst[e]], 1);
}

__global__ __launch_bounds__(1024) void scan1_kernel(const int* __restrict__ deg,
                                                     int* __restrict__ incl, int* __restrict__ bsum) {
    __shared__ int tmp[1024];
    int t = threadIdx.x, g = blockIdx.x * 1024 + t;
    tmp[t] = deg[g];
    __syncthreads();
    for (int off = 1; off < 1024; off <<= 1) {
        int x = (t >= off) ? tmp[t - off] : 0;
        __syncthreads();
        tmp[t] += x;
        __syncthreads();
    }
    incl[g] = tmp[t];
    if (t == 1023) bsum[blockIdx.x] = tmp[t];
}

__global__ __launch_bounds__(256) void scan2_kernel(const int* __restrict__ bsum, int* __restrict__ boff) {
    __shared__ int tmp[256];
    int t = threadIdx.x;
    int own = bsum[t];
    tmp[t] = own;
    __syncthreads();
    for (int off = 1; off < 256; off <<= 1) {
        int x = (t >= off) ? tmp[t - off] : 0;
        __syncthreads();
        tmp[t] += x;
        __syncthreads();
    }
    boff[t] = tmp[t] - own;
}

__global__ __launch_bounds__(256) void scan3_kernel(const int* __restrict__ incl, const int* __restrict__ deg,
                                                    const int* __restrict__ boff,
                                                    int* __restrict__ rowstart, int* __restrict__ cursor) {
    int g = blockIdx.x * 256 + threadIdx.x;
    int v = incl[g] - deg[g] + boff[g >> 10];
    rowstart[g] = v;
    cursor[g] = v;
}

__global__ __launch_bounds__(256) void scatter_kernel(const int* __restrict__ src, const int* __restrict__ dst,
                                                      int* __restrict__ cursor, int* __restrict__ csr) {
    int e = blockIdx.x * 256 + threadIdx.x;
    int slot = atomicAdd(&cursor[dst[e]], 1);
    csr[slot] = src[e];
}

// ---------- segment-sum gather: one wave per node (bf16 h -> bf16 agg) ----------
__global__ __launch_bounds__(256) void aggregate_kernel(
    const u16* __restrict__ h, const int* __restrict__ rowstart,
    const int* __restrict__ csr, u16* __restrict__ agg)
{
    const int wid = threadIdx.x >> 6, lane = threadIdx.x & 63;
    const int node = blockIdx.x * 4 + wid;
    const int beg = rowstart[node];
    const int end = (node == N_NODES - 1) ? N_EDGES : rowstart[node + 1];
    float a0 = 0.f, a1 = 0.f, a2 = 0.f, a3 = 0.f;
    for (int j = beg; j < end; ++j) {
        int s = csr[j];
        uint2 r = *(const uint2*)(h + (size_t)s * EMB + lane * 4);
        a0 += lo16(r.x); a1 += hi16(r.x); a2 += lo16(r.y); a3 += hi16(r.y);
    }
    uint2 out;
    out.x = (u32)f2bf(a0) | ((u32)f2bf(a1) << 16);
    out.y = (u32)f2bf(a2) | ((u32)f2bf(a3) << 16);
    *(uint2*)(agg + (size_t)node * EMB + lane * 4) = out;
}

// ---------- fused GEMM: relu([agg|h] @ [Wl|Wr]^T + bl) + h, then LayerNorm ----------
// BM=64, BN=256 (full width), BK=64, 256 threads = 4 waves, wave tile 64x64.
// F32OUT=false: write bf16 to outb (in-place over Ah allowed; block-local rows only).
// F32OUT=true:  write fp32 to outf (final d_out).
template<bool F32OUT>
__global__ __launch_bounds__(256, 3) void gemm_fused_kernel(
    const u16* __restrict__ Aagg, const u16* __restrict__ Ah,
    const u16* __restrict__ Wl, const u16* __restrict__ Wr,
    const float* __restrict__ bias, const float* __restrict__ gam, const float* __restrict__ bet,
    u16* __restrict__ outb, float* __restrict__ outf)
{
    __shared__ alignas(16) u16 lA[64 * 64];    // 8 KB
    __shared__ alignas(16) u16 lB[256 * 64];   // 32 KB
    __shared__ float s_sum[64];
    __shared__ float s_sq[64];

    const int tid = threadIdx.x;
    const int wid = tid >> 6, lane = tid & 63;
    const int quad = lane >> 4, l16 = lane & 15;
    const int m0 = blockIdx.x * 64;

    f32x4 acc[4][4] = {};

    for (int s = 0; s < 8; ++s) {
        const int k0 = s * 64;
        const u16* Asrc = (k0 < 256) ? (Aagg + k0) : (Ah + (k0 - 256));
        const u16* Bsrc = (k0 < 256) ? (Wl + k0) : (Wr + (k0 - 256));
        #pragma unroll
        for (int t = 0; t < 2; ++t) {   // A tile: 64 rows x 128 B = 8 KB, 8 insts, 2/wave
            int q = wid * 2 + t;
            int row = m0 + q * 8 + (lane >> 3);
            async_copy16((char*)lA + q * 1024, Asrc + (size_t)row * EMB + (lane & 7) * 8);
        }
        #pragma unroll
        for (int t = 0; t < 8; ++t) {   // B tile: 256 rows x 128 B = 32 KB, 32 insts, 8/wave
            int q = wid * 8 + t;
            int n = q * 8 + (lane >> 3);
            async_copy16((char*)lB + q * 1024, Bsrc + (size_t)n * EMB + (lane & 7) * 8);
        }
        __syncthreads();
        #pragma unroll
        for (int kk = 0; kk < 2; ++kk) {
            bf16x8 af[4], bfr[4];
            #pragma unroll
            for (int mt = 0; mt < 4; ++mt)
                af[mt] = *(const bf16x8*)&lA[(mt * 16 + l16) * 64 + kk * 32 + quad * 8];
            #pragma unroll
            for (int nt = 0; nt < 4; ++nt)
                bfr[nt] = *(const bf16x8*)&lB[(wid * 64 + nt * 16 + l16) * 64 + kk * 32 + quad * 8];
            #pragma unroll
            for (int mt = 0; mt < 4; ++mt)
                #pragma unroll
                for (int nt = 0; nt < 4; ++nt)
                    acc[mt][nt] = __builtin_amdgcn_mfma_f32_16x16x32_bf16(af[mt], bfr[nt], acc[mt][nt], 0, 0, 0);
        }
        __syncthreads();
    }

    // -------- epilogue: bias + relu + residual + LN --------
    if (tid < 64) { s_sum[tid] = 0.f; s_sq[tid] = 0.f; }
    __syncthreads();

    const int cb = wid * 64;
    float blv[4], gv[4], bv[4];
    #pragma unroll
    for (int nt = 0; nt < 4; ++nt) {
        int col = cb + nt * 16 + l16;
        blv[nt] = bias[col]; gv[nt] = gam[col]; bv[nt] = bet[col];
    }

    #pragma unroll
    for (int mt = 0; mt < 4; ++mt) {
        #pragma unroll
        for (int i = 0; i < 4; ++i) {
            int r = mt * 16 + quad * 4 + i;      // C/D: col=lane&15, row=quad*4+i (verified m89)
            int rowg = m0 + r;
            float rs = 0.f, rq = 0.f;
            #pragma unroll
            for (int nt = 0; nt < 4; ++nt) {
                int col = cb + nt * 16 + l16;
                float v = acc[mt][nt][i] + blv[nt];
                v = fmaxf(v, 0.f);
                v += bf2f(Ah[(size_t)rowg * EMB + col]);   // residual
                acc[mt][nt][i] = v;
                rs += v; rq += v * v;
            }
            #pragma unroll
            for (int m = 1; m < 16; m <<= 1) { rs += __shfl_xor(rs, m); rq += __shfl_xor(rq, m); }
            if (l16 == 0) { atomicAdd(&s_sum[r], rs); atomicAdd(&s_sq[r], rq); }
        }
    }
    __syncthreads();

    #pragma unroll
    for (int mt = 0; mt < 4; ++mt) {
        #pragma unroll
        for (int i = 0; i < 4; ++i) {
            int r = mt * 16 + quad * 4 + i;
            int rowg = m0 + r;
            float mean = s_sum[r] * (1.f / 256.f);
            float var = s_sq[r] * (1.f / 256.f) - mean * mean;
            float rstd = rsqrtf(var + LN_EPS);
            #pragma unroll
            for (int nt = 0; nt < 4; ++nt) {
                int col = cb + nt * 16 + l16;
                float o = (acc[mt][nt][i] - mean) * rstd * gv[nt] + bv[nt];
                if (F32OUT) outf[(size_t)rowg * EMB + col] = o;
                else        outb[(size_t)rowg * EMB + col] = f2bf(o);
            }
        }
    }
}

extern "C" void kernel_launch(void* const* d_in, const int* in_sizes, int n_in,
                              void* d_out, int out_size, void* d_ws, size_t ws_size,
                              hipStream_t stream)
{
    const int* node_emb = (const int*)d_in[0];
    const int* pos      = (const int*)d_in[1];
    const int* edge     = (const int*)d_in[2];
    const float* node_tab = (const float*)d_in[3];
    const float* pos_tab  = (const float*)d_in[4];
    const float* g_emb    = (const float*)d_in[5];
    const float* b_emb    = (const float*)d_in[6];
    const float* Wl0 = (const float*)d_in[7];
    const float* bl0 = (const float*)d_in[8];
    const float* Wr0 = (const float*)d_in[9];
    const float* g0  = (const float*)d_in[10];
    const float* b0  = (const float*)d_in[11];
    const float* Wl1 = (const float*)d_in[12];
    const float* bl1 = (const float*)d_in[13];
    const float* Wr1 = (const float*)d_in[14];
    const float* g1  = (const float*)d_in[15];
    const float* b1  = (const float*)d_in[16];

    char* w = (char*)d_ws;
    auto alloc = [&](size_t bytes) { char* p = w; w += (bytes + 255) & ~(size_t)255; return p; };
    u16* h0       = (u16*)alloc((size_t)N_NODES * EMB * 2);  // 134 MB (layer-0 in/out, in place)
    u16* agg      = (u16*)alloc((size_t)N_NODES * EMB * 2);  // 134 MB
    u16* wbf      = (u16*)alloc((size_t)4 * 65536 * 2);      // bf16 [Wl0|Wr0|Wl1|Wr1]
    int* deg      = (int*)alloc((size_t)N_NODES * 4);
    int* incl     = (int*)alloc((size_t)N_NODES * 4);
    int* rowstart = (int*)alloc((size_t)N_NODES * 4);
    int* cursor   = (int*)alloc((size_t)N_NODES * 4);
    int* csr      = (int*)alloc((size_t)N_EDGES * 4);
    int* bsum     = (int*)alloc(256 * 4);
    int* boff     = (int*)alloc(256 * 4);

    float* outf = (float*)d_out;   // reference output dtype is float32

    const int* srcv = edge;
    const int* dstv = edge + N_EDGES;

    hipMemsetAsync(deg, 0, (size_t)N_NODES * 4, stream);
    convert_w_kernel<<<256, 256, 0, stream>>>(Wl0, Wr0, Wl1, Wr1, wbf);
    embed_ln_kernel<<<N_NODES / 4, 256, 0, stream>>>(node_emb, pos, node_tab, pos_tab, g_emb, b_emb, h0);
    hist_kernel<<<N_EDGES / 256, 256, 0, stream>>>(dstv, deg);
    scan1_kernel<<<N_NODES / 1024, 1024, 0, stream>>>(deg, incl, bsum);
    scan2_kernel<<<1, 256, 0, stream>>>(bsum, boff);
    scan3_kernel<<<N_NODES / 256, 256, 0, stream>>>(incl, deg, boff, rowstart, cursor);
    scatter_kernel<<<N_EDGES / 256, 256, 0, stream>>>(srcv, dstv, cursor, csr);

    // layer 0: h0 -> h0 (in place; each block touches only its own 64 rows)
    aggregate_kernel<<<N_NODES / 4, 256, 0, stream>>>(h0, rowstart, csr, agg);
    gemm_fused_kernel<false><<<N_NODES / 64, 256, 0, stream>>>(agg, h0, wbf, wbf + 65536, bl0, g0, b0, h0, nullptr);
    // layer 1: h0 -> d_out (fp32)
    aggregate_kernel<<<N_NODES / 4, 256, 0, stream>>>(h0, rowstart, csr, agg);
    gemm_fused_kernel<true><<<N_NODES / 64, 256, 0, stream>>>(agg, h0, wbf + 131072, wbf + 196608, bl1, g1, b1, nullptr, outf);
}

// Round 5
// 983.332 us; speedup vs baseline: 1.0008x; 1.0008x over previous
//
#include <hip/hip_runtime.h>
#include <hip/hip_bf16.h>
#include <stdint.h>

#define N_NODES 262144
#define N_EDGES 524288
#define EMB 256
#define LN_EPS 1e-5f

typedef unsigned short u16;
typedef unsigned int u32;
typedef __bf16 bf16_t;
typedef __bf16 bf16x8 __attribute__((ext_vector_type(8)));
typedef float f32x4 __attribute__((ext_vector_type(4)));

__device__ __forceinline__ u16 f2bf(float f) {
    u32 u = __float_as_uint(f);
    u32 r = u + 0x7fffu + ((u >> 16) & 1u);
    return (u16)(r >> 16);
}
__device__ __forceinline__ float bf2f(u16 b) { return __uint_as_float(((u32)b) << 16); }
__device__ __forceinline__ float lo16(u32 x) { return __uint_as_float(x << 16); }
__device__ __forceinline__ float hi16(u32 x) { return __uint_as_float(x & 0xffff0000u); }

__device__ __forceinline__ void async_copy16(void* lds, const void* g) {
    __builtin_amdgcn_global_load_lds(
        (const __attribute__((address_space(1))) u32*)g,
        (__attribute__((address_space(3))) u32*)lds, 16, 0, 0);
}

// ---------- convert 4 weight matrices fp32 -> bf16 into ws ----------
__global__ __launch_bounds__(256) void convert_w_kernel(
    const float* __restrict__ a, const float* __restrict__ b,
    const float* __restrict__ c, const float* __restrict__ d,
    u16* __restrict__ out)
{
    int seg = blockIdx.x >> 6;       // 0..3
    int blk = blockIdx.x & 63;       // 0..63
    const float* src = (seg == 0) ? a : (seg == 1) ? b : (seg == 2) ? c : d;
    int off = blk * 1024 + threadIdx.x * 4;
    float4 v = *(const float4*)(src + off);
    uint2 o;
    o.x = (u32)f2bf(v.x) | ((u32)f2bf(v.y) << 16);
    o.y = (u32)f2bf(v.z) | ((u32)f2bf(v.w) << 16);
    *(uint2*)(out + seg * 65536 + off) = o;
}

// ---------- embed + layernorm: one wave per row (fp32 inputs -> bf16 h0) ----------
__global__ __launch_bounds__(256) void embed_ln_kernel(
    const int* __restrict__ node_emb, const int* __restrict__ pos,
    const float* __restrict__ node_tab, const float* __restrict__ pos_tab,
    const float* __restrict__ g_emb, const float* __restrict__ b_emb,
    u16* __restrict__ h0)
{
    const int wid = threadIdx.x >> 6, lane = threadIdx.x & 63;
    const int row = blockIdx.x * 4 + wid;
    const int idx = node_emb[row];
    const int p = pos[row];
    float4 ra = *(const float4*)(node_tab + (size_t)idx * EMB + lane * 4);
    float4 rb = *(const float4*)(pos_tab + (size_t)p * EMB + lane * 4);
    float v0 = ra.x * 16.f + rb.x;
    float v1 = ra.y * 16.f + rb.y;
    float v2 = ra.z * 16.f + rb.z;
    float v3 = ra.w * 16.f + rb.w;
    float s = v0 + v1 + v2 + v3;
    float sq = v0 * v0 + v1 * v1 + v2 * v2 + v3 * v3;
    #pragma unroll
    for (int m = 1; m < 64; m <<= 1) { s += __shfl_xor(s, m); sq += __shfl_xor(sq, m); }
    float mean = s * (1.f / 256.f);
    float var = sq * (1.f / 256.f) - mean * mean;
    float rstd = rsqrtf(var + LN_EPS);
    float4 rg = *(const float4*)(g_emb + lane * 4);
    float4 rbt = *(const float4*)(b_emb + lane * 4);
    float o0 = (v0 - mean) * rstd * rg.x + rbt.x;
    float o1 = (v1 - mean) * rstd * rg.y + rbt.y;
    float o2 = (v2 - mean) * rstd * rg.z + rbt.z;
    float o3 = (v3 - mean) * rstd * rg.w + rbt.w;
    uint2 out;
    out.x = (u32)f2bf(o0) | ((u32)f2bf(o1) << 16);
    out.y = (u32)f2bf(o2) | ((u32)f2bf(o3) << 16);
    *(uint2*)(h0 + (size_t)row * EMB + lane * 4) = out;
}

// ---------- CSR build ----------
__global__ __launch_bounds__(256) void hist_kernel(const int* __restrict__ dst, int* __restrict__ deg) {
    int e = blockIdx.x * 256 + threadIdx.x;
    atomicAdd(&deg[dst[e]], 1);
}

__global__ __launch_bounds__(1024) void scan1_kernel(const int* __restrict__ deg,
                                                     int* __restrict__ incl, int* __restrict__ bsum) {
    __shared__ int tmp[1024];
    int t = threadIdx.x, g = blockIdx.x * 1024 + t;
    tmp[t] = deg[g];
    __syncthreads();
    for (int off = 1; off < 1024; off <<= 1) {
        int x = (t >= off) ? tmp[t - off] : 0;
        __syncthreads();
        tmp[t] += x;
        __syncthreads();
    }
    incl[g] = tmp[t];
    if (t == 1023) bsum[blockIdx.x] = tmp[t];
}

__global__ __launch_bounds__(256) void scan2_kernel(const int* __restrict__ bsum, int* __restrict__ boff) {
    __shared__ int tmp[256];
    int t = threadIdx.x;
    int own = bsum[t];
    tmp[t] = own;
    __syncthreads();
    for (int off = 1; off < 256; off <<= 1) {
        int x = (t >= off) ? tmp[t - off] : 0;
        __syncthreads();
        tmp[t] += x;
        __syncthreads();
    }
    boff[t] = tmp[t] - own;
}

__global__ __launch_bounds__(256) void scan3_kernel(const int* __restrict__ incl, const int* __restrict__ deg,
                                                    const int* __restrict__ boff,
                                                    int* __restrict__ rowstart, int* __restrict__ cursor) {
    int g = blockIdx.x * 256 + threadIdx.x;
    int v = incl[g] - deg[g] + boff[g >> 10];
    rowstart[g] = v;
    cursor[g] = v;
}

__global__ __launch_bounds__(256) void scatter_kernel(const int* __restrict__ src, const int* __restrict__ dst,
                                                      int* __restrict__ cursor, int* __restrict__ csr) {
    int e = blockIdx.x * 256 + threadIdx.x;
    int slot = atomicAdd(&cursor[dst[e]], 1);
    csr[slot] = src[e];
}

// ---------- segment-sum gather: one wave per node, 32 lanes per row, 2 rows in flight ----------
__global__ __launch_bounds__(256) void aggregate_kernel(
    const u16* __restrict__ h, const int* __restrict__ rowstart,
    const int* __restrict__ csr, u16* __restrict__ agg)
{
    const int wid = threadIdx.x >> 6, lane = threadIdx.x & 63;
    const int node = blockIdx.x * 4 + wid;
    const int beg = rowstart[node];
    const int end = (node == N_NODES - 1) ? N_EDGES : rowstart[node + 1];
    const int half = lane >> 5;       // 0: edge j, 1: edge j+1
    const int col8 = lane & 31;       // 8-col group within the row
    float a[8] = {};
    for (int j = beg; j < end; j += 2) {
        int jj = j + half;
        bool valid = jj < end;
        int s = csr[valid ? jj : j];
        uint4 r = *(const uint4*)(h + (size_t)s * EMB + col8 * 8);
        if (valid) {
            a[0] += lo16(r.x); a[1] += hi16(r.x);
            a[2] += lo16(r.y); a[3] += hi16(r.y);
            a[4] += lo16(r.z); a[5] += hi16(r.z);
            a[6] += lo16(r.w); a[7] += hi16(r.w);
        }
    }
    #pragma unroll
    for (int k = 0; k < 8; ++k) a[k] += __shfl_xor(a[k], 32);
    if (half == 0) {
        uint4 o;
        o.x = (u32)f2bf(a[0]) | ((u32)f2bf(a[1]) << 16);
        o.y = (u32)f2bf(a[2]) | ((u32)f2bf(a[3]) << 16);
        o.z = (u32)f2bf(a[4]) | ((u32)f2bf(a[5]) << 16);
        o.w = (u32)f2bf(a[6]) | ((u32)f2bf(a[7]) << 16);
        *(uint4*)(agg + (size_t)node * EMB + col8 * 8) = o;
    }
}

// ---------- fused GEMM: relu([agg|h] @ [Wl|Wr]^T + bl) + h, then LayerNorm ----------
// BM=128, BN=256 (full width), BK=64, 512 threads = 8 waves (2 row-groups x 4 col-groups),
// wave tile 64x64. LDS k-group XOR swizzle (kg ^= row&7) kills the 16-way bank conflicts
// while staying global_load_lds-compatible (permute source addresses, not LDS layout).
template<bool F32OUT>
__global__ __launch_bounds__(512, 2) void gemm_fused_kernel(
    const u16* __restrict__ Aagg, const u16* __restrict__ Ah,
    const u16* __restrict__ Wl, const u16* __restrict__ Wr,
    const float* __restrict__ bias, const float* __restrict__ gam, const float* __restrict__ bet,
    u16* __restrict__ outb, float* __restrict__ outf)
{
    __shared__ alignas(16) u16 lA[128 * 64];   // 16 KB (swizzled)
    __shared__ alignas(16) u16 lB[256 * 64];   // 32 KB (swizzled)
    __shared__ float s_sum[128];
    __shared__ float s_sq[128];

    const int tid = threadIdx.x;
    const int wid = tid >> 6, lane = tid & 63;
    const int quad = lane >> 4, l16 = lane & 15;
    const int wrow = wid >> 2, wcol = wid & 3;
    const int m0 = blockIdx.x * 128;
    // source k-offset (u16) for this lane's 16B chunk: kg = (lane&7) ^ (row&7), row&7 = lane>>3
    const int lsrc = ((lane & 7) ^ (lane >> 3)) * 8;

    f32x4 acc[4][4] = {};

    for (int s = 0; s < 8; ++s) {
        const int k0 = s * 64;
        const u16* Asrc = (k0 < 256) ? (Aagg + k0) : (Ah + (k0 - 256));
        const u16* Bsrc = (k0 < 256) ? (Wl + k0) : (Wr + (k0 - 256));
        #pragma unroll
        for (int t = 0; t < 2; ++t) {   // A tile: 128 rows x 128 B = 16 KB, 16 insts, 2/wave
            int q = wid * 2 + t;
            int row = m0 + q * 8 + (lane >> 3);
            async_copy16((char*)lA + q * 1024, Asrc + (size_t)row * EMB + lsrc);
        }
        #pragma unroll
        for (int t = 0; t < 4; ++t) {   // B tile: 256 rows x 128 B = 32 KB, 32 insts, 4/wave
            int q = wid * 4 + t;
            int n = q * 8 + (lane >> 3);
            async_copy16((char*)lB + q * 1024, Bsrc + (size_t)n * EMB + lsrc);
        }
        __syncthreads();
        #pragma unroll
        for (int kk = 0; kk < 2; ++kk) {
            const int g = (((kk * 4 + quad) ^ (l16 & 7)) * 8);  // un-swizzle on read
            bf16x8 af[4], bfr[4];
            #pragma unroll
            for (int mt = 0; mt < 4; ++mt)
                af[mt] = *(const bf16x8*)&lA[(wrow * 64 + mt * 16 + l16) * 64 + g];
            #pragma unroll
            for (int nt = 0; nt < 4; ++nt)
                bfr[nt] = *(const bf16x8*)&lB[(wcol * 64 + nt * 16 + l16) * 64 + g];
            #pragma unroll
            for (int mt = 0; mt < 4; ++mt)
                #pragma unroll
                for (int nt = 0; nt < 4; ++nt)
                    acc[mt][nt] = __builtin_amdgcn_mfma_f32_16x16x32_bf16(af[mt], bfr[nt], acc[mt][nt], 0, 0, 0);
        }
        __syncthreads();
    }

    // -------- epilogue: bias + relu + residual + LN --------
    if (tid < 128) { s_sum[tid] = 0.f; s_sq[tid] = 0.f; }
    __syncthreads();

    const int cb = wcol * 64;
    float blv[4], gv[4], bv[4];
    #pragma unroll
    for (int nt = 0; nt < 4; ++nt) {
        int col = cb + nt * 16 + l16;
        blv[nt] = bias[col]; gv[nt] = gam[col]; bv[nt] = bet[col];
    }

    #pragma unroll
    for (int mt = 0; mt < 4; ++mt) {
        #pragma unroll
        for (int i = 0; i < 4; ++i) {
            int r = wrow * 64 + mt * 16 + quad * 4 + i;   // C/D: col=lane&15, row=quad*4+i (m89)
            int rowg = m0 + r;
            float rs = 0.f, rq = 0.f;
            #pragma unroll
            for (int nt = 0; nt < 4; ++nt) {
                int col = cb + nt * 16 + l16;
                float v = acc[mt][nt][i] + blv[nt];
                v = fmaxf(v, 0.f);
                v += bf2f(Ah[(size_t)rowg * EMB + col]);   // residual
                acc[mt][nt][i] = v;
                rs += v; rq += v * v;
            }
            #pragma unroll
            for (int m = 1; m < 16; m <<= 1) { rs += __shfl_xor(rs, m); rq += __shfl_xor(rq, m); }
            if (l16 == 0) { atomicAdd(&s_sum[r], rs); atomicAdd(&s_sq[r], rq); }
        }
    }
    __syncthreads();

    #pragma unroll
    for (int mt = 0; mt < 4; ++mt) {
        #pragma unroll
        for (int i = 0; i < 4; ++i) {
            int r = wrow * 64 + mt * 16 + quad * 4 + i;
            int rowg = m0 + r;
            float mean = s_sum[r] * (1.f / 256.f);
            float var = s_sq[r] * (1.f / 256.f) - mean * mean;
            float rstd = rsqrtf(var + LN_EPS);
            #pragma unroll
            for (int nt = 0; nt < 4; ++nt) {
                int col = cb + nt * 16 + l16;
                float o = (acc[mt][nt][i] - mean) * rstd * gv[nt] + bv[nt];
                if (F32OUT) outf[(size_t)rowg * EMB + col] = o;
                else        outb[(size_t)rowg * EMB + col] = f2bf(o);
            }
        }
    }
}

extern "C" void kernel_launch(void* const* d_in, const int* in_sizes, int n_in,
                              void* d_out, int out_size, void* d_ws, size_t ws_size,
                              hipStream_t stream)
{
    const int* node_emb = (const int*)d_in[0];
    const int* pos      = (const int*)d_in[1];
    const int* edge     = (const int*)d_in[2];
    const float* node_tab = (const float*)d_in[3];
    const float* pos_tab  = (const float*)d_in[4];
    const float* g_emb    = (const float*)d_in[5];
    const float* b_emb    = (const float*)d_in[6];
    const float* Wl0 = (const float*)d_in[7];
    const float* bl0 = (const float*)d_in[8];
    const float* Wr0 = (const float*)d_in[9];
    const float* g0  = (const float*)d_in[10];
    const float* b0  = (const float*)d_in[11];
    const float* Wl1 = (const float*)d_in[12];
    const float* bl1 = (const float*)d_in[13];
    const float* Wr1 = (const float*)d_in[14];
    const float* g1  = (const float*)d_in[15];
    const float* b1  = (const float*)d_in[16];

    char* w = (char*)d_ws;
    auto alloc = [&](size_t bytes) { char* p = w; w += (bytes + 255) & ~(size_t)255; return p; };
    u16* h0       = (u16*)alloc((size_t)N_NODES * EMB * 2);  // 134 MB (layer-0 in/out, in place)
    u16* agg      = (u16*)alloc((size_t)N_NODES * EMB * 2);  // 134 MB
    u16* wbf      = (u16*)alloc((size_t)4 * 65536 * 2);      // bf16 [Wl0|Wr0|Wl1|Wr1]
    int* deg      = (int*)alloc((size_t)N_NODES * 4);
    int* incl     = (int*)alloc((size_t)N_NODES * 4);
    int* rowstart = (int*)alloc((size_t)N_NODES * 4);
    int* cursor   = (int*)alloc((size_t)N_NODES * 4);
    int* csr      = (int*)alloc((size_t)N_EDGES * 4);
    int* bsum     = (int*)alloc(256 * 4);
    int* boff     = (int*)alloc(256 * 4);

    float* outf = (float*)d_out;   // reference output dtype is float32

    const int* srcv = edge;
    const int* dstv = edge + N_EDGES;

    hipMemsetAsync(deg, 0, (size_t)N_NODES * 4, stream);
    convert_w_kernel<<<256, 256, 0, stream>>>(Wl0, Wr0, Wl1, Wr1, wbf);
    embed_ln_kernel<<<N_NODES / 4, 256, 0, stream>>>(node_emb, pos, node_tab, pos_tab, g_emb, b_emb, h0);
    hist_kernel<<<N_EDGES / 256, 256, 0, stream>>>(dstv, deg);
    scan1_kernel<<<N_NODES / 1024, 1024, 0, stream>>>(deg, incl, bsum);
    scan2_kernel<<<1, 256, 0, stream>>>(bsum, boff);
    scan3_kernel<<<N_NODES / 256, 256, 0, stream>>>(incl, deg, boff, rowstart, cursor);
    scatter_kernel<<<N_EDGES / 256, 256, 0, stream>>>(srcv, dstv, cursor, csr);

    // layer 0: h0 -> h0 (in place; each block touches only its own 128 rows)
    aggregate_kernel<<<N_NODES / 4, 256, 0, stream>>>(h0, rowstart, csr, agg);
    gemm_fused_kernel<false><<<N_NODES / 128, 512, 0, stream>>>(agg, h0, wbf, wbf + 65536, bl0, g0, b0, h0, nullptr);
    // layer 1: h0 -> d_out (fp32)
    aggregate_kernel<<<N_NODES / 4, 256, 0, stream>>>(h0, rowstart, csr, agg);
    gemm_fused_kernel<true><<<N_NODES / 128, 512, 0, stream>>>(agg, h0, wbf + 131072, wbf + 196608, bl1, g1, b1, nullptr, outf);
}